// Round 6
// baseline (390.223 us; speedup 1.0000x reference)
//
#include <hip/hip_runtime.h>

#define NN 10000      // nodes
#define NE 320000     // edges (before self-loops)
#define NB 64         // graphs
#define CIN 128       // in_channels
#define CEC 64        // edge_channels
#define CHID 256      // hidden
#define CMLP 512
#define CNC 4
#define K1 (2 * CIN + CEC)    // 320
#define K23 (2 * CHID + CEC)  // 576

static __host__ int cdiv(int a, int b) { return (a + b - 1) / b; }

typedef short sfrag __attribute__((ext_vector_type(8)));   // 8 bf16 in 4 VGPRs
typedef float f4 __attribute__((ext_vector_type(4)));
typedef float f2 __attribute__((ext_vector_type(2)));

static __device__ __forceinline__ ushort f2b(float f) {
  union { float f; unsigned u; } v; v.f = f;
  unsigned r = (v.u + 0x7fffu + ((v.u >> 16) & 1u)) >> 16;
  return (ushort)r;
}
static __device__ __forceinline__ float b2f(ushort u) {
  union { unsigned u; float f; } v; v.u = ((unsigned)u) << 16;
  return v.f;
}

// ---------------- zero the per-launch accumulators (workspace is POISONED each iteration) ----------------
__global__ __launch_bounds__(256) void k_init(int* __restrict__ ptr, float* __restrict__ stats) {
  int i = blockIdx.x * 256 + threadIdx.x;
  if (i <= NN) ptr[i] = 0;
  if (i < 6 * CHID) stats[i] = 0.f;
}

// ---------------- edge-degree histogram into ptr[d+1] ----------------
__global__ __launch_bounds__(256) void k_count(const int* __restrict__ ei, int* __restrict__ ptr) {
  int e = blockIdx.x * 256 + threadIdx.x;  // 1250*256 == NE exactly
  atomicAdd(&ptr[ei[NE + e] + 1], 1);
}

// ---------------- one-block scan: ptr(histogram) -> rowp/pos/degf ----------------
#define SC 10
__global__ __launch_bounds__(1024) void k_scan(const int* __restrict__ ptr, int* __restrict__ rowp,
                                               int* __restrict__ pos, float* __restrict__ degf) {
  int t = threadIdx.x;
  int base = t * SC;
  int v[SC];
#pragma unroll
  for (int j = 0; j < SC; ++j) {
    int i = base + j;
    v[j] = (i <= NN) ? ptr[i] : 0;
  }
  int bnd;  // orig[base+SC]
  { int i = base + SC; bnd = (i <= NN) ? ptr[i] : 0; }
#pragma unroll
  for (int j = 1; j < SC; ++j) v[j] += v[j - 1];
  int tot = v[SC - 1];
  int lane = t & 63, wid = t >> 6;
  int sc = tot;
#pragma unroll
  for (int d = 1; d < 64; d <<= 1) {
    int tt = __shfl_up(sc, d);
    if (lane >= d) sc += tt;
  }
  __shared__ int ws[16];
  if (lane == 63) ws[wid] = sc;
  __syncthreads();
  int add = 0;
#pragma unroll
  for (int w2 = 0; w2 < 16; ++w2) if (w2 < wid) add += ws[w2];
  int pre = add + sc - tot;  // exclusive prefix of this thread's chunk
#pragma unroll
  for (int j = 0; j < SC; ++j) {
    int i = base + j;
    if (i > NN) break;
    int fin = pre + v[j];  // inclusive sum over orig[0..i] == CSR row start of i
    rowp[i] = fin;
    if (i < NN) {
      pos[i] = fin;
      int nxtorig = (j + 1 < SC) ? (v[j + 1] - v[j]) : bnd;
      degf[i] = (float)(nxtorig + 1);  // degree + self-loop
    }
  }
}

// ---------------- counting-sort placement: se[slot] = {src, orig-edge} (one 8B scatter) ----------------
__global__ __launch_bounds__(256) void k_fill(const int* __restrict__ ei, int* __restrict__ pos,
                                              int2* __restrict__ se) {
  int e = blockIdx.x * 256 + threadIdx.x;  // 1250*256 == NE
  int d = ei[NE + e];
  int idx = atomicAdd(&pos[d], 1);
  se[idx] = make_int2(ei[e], e);
}

// ---------------- prep: [0,1250) A1[:,0:128]=bf16(degf*x), xb=bf16(x); [1250,2722) Wt transposes ----------------
__global__ __launch_bounds__(256) void k_prep(const float4* __restrict__ x,
                                              const float* __restrict__ degf, ushort* __restrict__ A1,
                                              ushort* __restrict__ xb, const float* __restrict__ W1,
                                              const float* __restrict__ W2, const float* __restrict__ W3,
                                              ushort* __restrict__ Wt1, ushort* __restrict__ Wt2,
                                              ushort* __restrict__ Wt3) {
  int b = blockIdx.x;
  int tid = threadIdx.x;
  if (b < 1250) {
    int gid = b * 256 + tid;  // NN*32 = 320000
    int node = gid >> 5;
    int c4 = (gid & 31) << 2;
    float d = degf[node];
    float4 v = x[gid];
    ushort4 o = { f2b(d * v.x), f2b(d * v.y), f2b(d * v.z), f2b(d * v.w) };
    *(ushort4*)&A1[(size_t)node * K1 + c4] = o;
    ushort4 xo = { f2b(v.x), f2b(v.y), f2b(v.z), f2b(v.w) };
    *(ushort4*)&xb[(size_t)node * CIN + c4] = xo;
  } else {
    int j = (b - 1250) * 256 + tid;  // 256*(K1+2*K23) = 376832
    const float* W; ushort* Wt; int Ktot;
    if (j < 256 * K1) { W = W1; Wt = Wt1; Ktot = K1; }
    else {
      j -= 256 * K1;
      if (j < 256 * K23) { W = W2; Wt = Wt2; Ktot = K23; }
      else { j -= 256 * K23; W = W3; Wt = Wt3; Ktot = K23; }
    }
    int n = j / Ktot;
    int k = j - n * Ktot;
    Wt[j] = f2b(W[(size_t)k * CHID + n]);
  }
}

// ---------------- fused: ea_sum (fp32 direct gather, 4 rows/instr) + layer-1 x-gather ----------------
__global__ __launch_bounds__(256) void k_eag(const float4* __restrict__ eattr4,
                                             const ushort* __restrict__ xb,
                                             const int* __restrict__ rowp, const int2* __restrict__ se,
                                             ushort* __restrict__ A1, ushort* __restrict__ A23) {
  int node = blockIdx.x * 4 + (threadIdx.x >> 6);
  int lane = threadIdx.x & 63;
  int s = rowp[node], e = rowp[node + 1];
  int nrows = e - s;

  // ea-sum: 16 lanes/row (float4/lane = full 256B row), 4 rows per load instruction,
  // gathered straight from the fp32 input (L3-resident) -- no fp8 intermediate.
  const int lrow = lane >> 4;   // 0..3: row within group-of-4
  const int lch = lane & 15;    // float4 slot within the 64-ch row
  f4 a = (f4){0.f, 0.f, 0.f, 0.f};
  int full4 = nrows & ~3;
  for (int r0 = 0; r0 < full4; r0 += 4) {
    int eo = se[s + r0 + lrow].y;
    float4 v = eattr4[(size_t)eo * 16 + lch];
    a.x += v.x; a.y += v.y; a.z += v.z; a.w += v.w;
  }
  if (full4 + lrow < nrows) {
    int eo = se[s + full4 + lrow].y;
    float4 v = eattr4[(size_t)eo * 16 + lch];
    a.x += v.x; a.y += v.y; a.z += v.z; a.w += v.w;
  }
#pragma unroll
  for (int m = 16; m < 64; m <<= 1) {
    a.x += __shfl_xor(a.x, m); a.y += __shfl_xor(a.y, m);
    a.z += __shfl_xor(a.z, m); a.w += __shfl_xor(a.w, m);
  }
  if (lane < 16) {  // +1.0 self-loop; lane writes channels 4*lane..+3
    ushort4 o = { f2b(a.x + 1.f), f2b(a.y + 1.f), f2b(a.z + 1.f), f2b(a.w + 1.f) };
    *(ushort4*)&A1[(size_t)node * K1 + 2 * CIN + lane * 4] = o;
    *(ushort4*)&A23[(size_t)node * K23 + 2 * CHID + lane * 4] = o;
  }

  // layer-1 gather: 32-wide pipelined chunks, uniform-break tail
  ushort2 own = *(const ushort2*)&xb[(size_t)node * CIN + lane * 2];
  float gx = b2f(own.x), gy = b2f(own.y);
  int myi = (lane < 32 && s + lane < e) ? se[s + lane].x : 0;
  for (int k0 = s; k0 < e; k0 += 32) {
    int rem = e - k0;
    int cur = myi;
    int nk = k0 + 32;
    if (nk < e) myi = (lane < 32 && nk + lane < e) ? se[nk + lane].x : 0;
    if (rem >= 32) {
#pragma unroll
      for (int j = 0; j < 32; ++j) {
        int idx = __shfl(cur, j);
        ushort2 v = *(const ushort2*)&xb[(size_t)idx * CIN + lane * 2];
        gx += b2f(v.x); gy += b2f(v.y);
      }
    } else {
#pragma unroll
      for (int j = 0; j < 32; ++j) {
        if (j >= rem) break;  // wave-uniform: no load issued past rem
        int idx = __shfl(cur, j);
        ushort2 v = *(const ushort2*)&xb[(size_t)idx * CIN + lane * 2];
        gx += b2f(v.x); gy += b2f(v.y);
      }
    }
  }
  ushort2 go = { f2b(gx), f2b(gy) };
  *(ushort2*)&A1[(size_t)node * K1 + CIN + lane * 2] = go;
}

// ---------------- layers 2/3: fused BN-apply + gather ----------------
__global__ __launch_bounds__(256) void k_gbn(const ushort* __restrict__ tmp, const unsigned* __restrict__ t8,
                                             const float* __restrict__ colsum, const float* __restrict__ colsq,
                                             const float* __restrict__ g, const float* __restrict__ be,
                                             const int* __restrict__ rowp, const int2* __restrict__ se,
                                             const float* __restrict__ degf, ushort* __restrict__ A23) {
  int node = blockIdx.x * 4 + (threadIdx.x >> 6);
  int lane = threadIdx.x & 63;
  int c4 = lane << 2;
  float sc[4], sh[4];
#pragma unroll
  for (int j = 0; j < 4; ++j) {
    int c = c4 + j;
    float mu = colsum[c] * (1.f / (float)NN);
    float var = colsq[c] * (1.f / (float)NN) - mu * mu;
    float inv = rsqrtf(var + 1e-5f);
    sc[j] = g[c] * inv;
    sh[j] = be[c] - mu * sc[j];
  }
  ushort4 tv = *(const ushort4*)&tmp[(size_t)node * CHID + c4];
  float o0 = fmaxf(fmaf(b2f(tv.x), sc[0], sh[0]), 0.f);
  float o1 = fmaxf(fmaf(b2f(tv.y), sc[1], sh[1]), 0.f);
  float o2 = fmaxf(fmaf(b2f(tv.z), sc[2], sh[2]), 0.f);
  float o3 = fmaxf(fmaf(b2f(tv.w), sc[3], sh[3]), 0.f);
  float d = degf[node];
  ushort4 ao = { f2b(d * o0), f2b(d * o1), f2b(d * o2), f2b(d * o3) };
  *(ushort4*)&A23[(size_t)node * K23 + c4] = ao;

  float ax = o0, ay = o1, az = o2, aw = o3;
  int s = rowp[node], e = rowp[node + 1];
  int myi = (lane < 32 && s + lane < e) ? se[s + lane].x : 0;
  for (int k0 = s; k0 < e; k0 += 32) {
    int rem = e - k0;
    int cur = myi;
    int nk = k0 + 32;
    if (nk < e) myi = (lane < 32 && nk + lane < e) ? se[nk + lane].x : 0;
    if (rem >= 32) {
#pragma unroll
      for (int j = 0; j < 32; ++j) {
        int idx = __shfl(cur, j);
        unsigned u = t8[(size_t)idx * 64 + lane];
        f2 lo = __builtin_amdgcn_cvt_pk_f32_fp8(u, false);
        f2 hi = __builtin_amdgcn_cvt_pk_f32_fp8(u, true);
        ax += fmaxf(fmaf(lo.x, sc[0], sh[0]), 0.f);
        ay += fmaxf(fmaf(lo.y, sc[1], sh[1]), 0.f);
        az += fmaxf(fmaf(hi.x, sc[2], sh[2]), 0.f);
        aw += fmaxf(fmaf(hi.y, sc[3], sh[3]), 0.f);
      }
    } else {
#pragma unroll
      for (int j = 0; j < 32; ++j) {
        if (j >= rem) break;  // wave-uniform: no load issued past rem
        int idx = __shfl(cur, j);
        unsigned u = t8[(size_t)idx * 64 + lane];
        f2 lo = __builtin_amdgcn_cvt_pk_f32_fp8(u, false);
        f2 hi = __builtin_amdgcn_cvt_pk_f32_fp8(u, true);
        ax += fmaxf(fmaf(lo.x, sc[0], sh[0]), 0.f);
        ay += fmaxf(fmaf(lo.y, sc[1], sh[1]), 0.f);
        az += fmaxf(fmaf(hi.x, sc[2], sh[2]), 0.f);
        aw += fmaxf(fmaf(hi.y, sc[3], sh[3]), 0.f);
      }
    }
  }
  ushort4 o = { f2b(ax), f2b(ay), f2b(az), f2b(aw) };
  *(ushort4*)&A23[(size_t)node * K23 + CHID + c4] = o;
}

// ---------------- MFMA GEMM (128x64 tile, register-prefetch dbuf, R0-exact) ----------------
__global__ __launch_bounds__(256) void k_gemm(const ushort* __restrict__ Ag, const ushort* __restrict__ Wt,
                                              const float* __restrict__ bias, const float* __restrict__ degf,
                                              ushort* __restrict__ outb, unsigned char* __restrict__ out8,
                                              float* __restrict__ colsum, float* __restrict__ colsq, int Ktot) {
  __shared__ ushort As[128 * 40];  // 128 rows x 32 k, stride 40
  __shared__ ushort Bs[64 * 40];   // 64 n x 32 k
  const int bm = blockIdx.x * 128;
  const int bn = blockIdx.y * 64;
  const int tid = threadIdx.x;
  const int w = tid >> 6;
  const int lane = tid & 63;
  const int ln = lane & 15;
  const int quad = lane >> 4;

  f4 acc[2][4];
#pragma unroll
  for (int mf = 0; mf < 2; ++mf)
#pragma unroll
    for (int nf = 0; nf < 4; ++nf) acc[mf][nf] = (f4){0.f, 0.f, 0.f, 0.f};

  const int rA = tid >> 1;
  const int hk = (tid & 1) << 4;  // 0 or 16
  const int rowA = bm + rA;
  const int nB = tid >> 2;
  const int kq = (tid & 3) << 3;  // 0,8,16,24
  const ushort* ap = Ag + (size_t)min(rowA, NN - 1) * Ktot + hk;
  const ushort* bp = Wt + (size_t)(bn + nB) * Ktot + kq;

  const int iters = Ktot >> 5;
  uint4 av0 = ((const uint4*)ap)[0];
  uint4 av1 = ((const uint4*)ap)[1];
  uint4 bv = *(const uint4*)bp;
  for (int it = 0; it < iters; ++it) {
    *(uint4*)&As[rA * 40 + hk] = av0;
    *(uint4*)&As[rA * 40 + hk + 8] = av1;
    *(uint4*)&Bs[nB * 40 + kq] = bv;
    __syncthreads();
    if (it + 1 < iters) {  // prefetch next K-tile while MFMAs consume LDS
      const ushort* apn = ap + (it + 1) * 32;
      av0 = ((const uint4*)apn)[0];
      av1 = ((const uint4*)apn)[1];
      bv = *(const uint4*)(bp + (it + 1) * 32);
    }
    sfrag a0 = *(const sfrag*)&As[(w * 32 + ln) * 40 + quad * 8];
    sfrag a1 = *(const sfrag*)&As[(w * 32 + 16 + ln) * 40 + quad * 8];
#pragma unroll
    for (int nf = 0; nf < 4; ++nf) {
      sfrag b = *(const sfrag*)&Bs[(nf * 16 + ln) * 40 + quad * 8];
      acc[0][nf] = __builtin_amdgcn_mfma_f32_16x16x32_bf16(a0, b, acc[0][nf], 0, 0, 0);
      acc[1][nf] = __builtin_amdgcn_mfma_f32_16x16x32_bf16(a1, b, acc[1][nf], 0, 0, 0);
    }
    __syncthreads();
  }

  float bcol[4];
#pragma unroll
  for (int nf = 0; nf < 4; ++nf) bcol[nf] = bias[bn + nf * 16 + ln];
  float ssum[4] = {0.f, 0.f, 0.f, 0.f}, sqq[4] = {0.f, 0.f, 0.f, 0.f};
#pragma unroll
  for (int mf = 0; mf < 2; ++mf) {
    int rbase = bm + w * 32 + mf * 16 + quad * 4;
#pragma unroll
    for (int r = 0; r < 4; ++r) {
      int row = rbase + r;
      bool valid = row < NN;
      float d = valid ? degf[row] : 0.f;
#pragma unroll
      for (int nf = 0; nf < 4; ++nf) {
        float v = fmaxf(acc[mf][nf][r] + d * bcol[nf], 0.f);
        if (valid) {
          size_t oidx = (size_t)row * CHID + bn + nf * 16 + ln;
          outb[oidx] = f2b(v);
          int enc = __builtin_amdgcn_cvt_pk_fp8_f32(v, v, 0, false);
          out8[oidx] = (unsigned char)enc;
          ssum[nf] += v;
          sqq[nf] += v * v;
        }
      }
    }
  }
#pragma unroll
  for (int nf = 0; nf < 4; ++nf) {
    float s = ssum[nf], q = sqq[nf];
    s += __shfl_xor(s, 16); s += __shfl_xor(s, 32);
    q += __shfl_xor(q, 16); q += __shfl_xor(q, 32);
    if (quad == 0) {
      atomicAdd(&colsum[bn + nf * 16 + ln], s);
      atomicAdd(&colsq[bn + nf * 16 + ln], q);
    }
  }
}

// ---------------- fused: per-graph BN+relu pooling + MLP head (one block per graph) ----------------
__global__ __launch_bounds__(512) void k_poolmlp(const ushort* __restrict__ t3, const float* __restrict__ colsum,
                                                 const float* __restrict__ colsq, const float* __restrict__ g3,
                                                 const float* __restrict__ be3, const int* __restrict__ batch,
                                                 const float* __restrict__ nb, const float* __restrict__ w1,
                                                 const float* __restrict__ b1, const float* __restrict__ w2,
                                                 const float* __restrict__ b2, float* __restrict__ out) {
  int g = blockIdx.x;
  int t = threadIdx.x;
  __shared__ int sgs, sge;
  __shared__ f4 pq[8][64];                 // 8 row-offset partials x 64 col-groups
  __shared__ float zin[CHID + 1 + CIN];    // 385
  __shared__ float red[8];
  if (t == 0) { sgs = NN; sge = 0; }
  __syncthreads();
  for (int i = t; i < NN; i += 512) {
    if (batch[i] == g) { atomicMin(&sgs, i); atomicMax(&sge, i + 1); }
  }
  __syncthreads();
  int gs = sgs, ge = sge;
  int cnt = (ge > gs) ? (ge - gs) : 0;

  int cg = t & 63, off = t >> 6;
  int c0 = cg << 2;
  float scv[4], shv[4];
#pragma unroll
  for (int j = 0; j < 4; ++j) {
    int c = c0 + j;
    float mu = colsum[c] * (1.f / (float)NN);
    float var = colsq[c] * (1.f / (float)NN) - mu * mu;
    float inv = rsqrtf(var + 1e-5f);
    scv[j] = g3[c] * inv;
    shv[j] = be3[c] - mu * scv[j];
  }
  f4 acc = (f4){0.f, 0.f, 0.f, 0.f};
  for (int r = gs + off; r < ge; r += 8) {
    ushort4 tv = *(const ushort4*)&t3[(size_t)r * CHID + c0];
    acc.x += fmaxf(fmaf(b2f(tv.x), scv[0], shv[0]), 0.f);
    acc.y += fmaxf(fmaf(b2f(tv.y), scv[1], shv[1]), 0.f);
    acc.z += fmaxf(fmaf(b2f(tv.z), scv[2], shv[2]), 0.f);
    acc.w += fmaxf(fmaf(b2f(tv.w), scv[3], shv[3]), 0.f);
  }
  pq[off][cg] = acc;
  __syncthreads();
  if (t < CHID) {
    float s = 0.f;
#pragma unroll
    for (int o = 0; o < 8; ++o) s += ((const float*)&pq[o][t >> 2])[t & 3];
    zin[t] = s;
  } else if (t == CHID) zin[CHID] = (float)cnt * 0.025f;  // / MAX_SIZE(40)
  else if (t < CHID + 1 + CIN) zin[t] = nb[g * CIN + (t - CHID - 1)];
  __syncthreads();

  float acc1 = b1[t];
  for (int k = 0; k < CHID + 1 + CIN; ++k) acc1 = fmaf(zin[k], w1[k * CMLP + t], acc1);
  float z = fmaxf(acc1, 0.f);
  int wid = t >> 6, wl = t & 63;
#pragma unroll
  for (int n = 0; n < CNC; ++n) {
    float part = z * w2[t * CNC + n];
#pragma unroll
    for (int d = 1; d < 64; d <<= 1) part += __shfl_xor(part, d);
    if (wl == 0) red[wid] = part;
    __syncthreads();
    if (t == 0) {
      float tot = 0.f;
#pragma unroll
      for (int i = 0; i < 8; ++i) tot += red[i];
      out[g * CNC + n] = tot + b2[n];
    }
    __syncthreads();
  }
}

// ---------------- launch ----------------

extern "C" void kernel_launch(void* const* d_in, const int* in_sizes, int n_in,
                              void* d_out, int out_size, void* d_ws, size_t ws_size,
                              hipStream_t stream) {
  const float* x     = (const float*)d_in[0];
  const int*   ei    = (const int*)d_in[1];
  const float* eattr = (const float*)d_in[2];
  const int*   batch = (const int*)d_in[3];
  const float* nbr   = (const float*)d_in[4];
  const float* W1 = (const float*)d_in[5];
  const float* b1 = (const float*)d_in[6];
  const float* g1 = (const float*)d_in[7];
  const float* be1 = (const float*)d_in[8];
  const float* W2 = (const float*)d_in[9];
  const float* b2 = (const float*)d_in[10];
  const float* g2 = (const float*)d_in[11];
  const float* be2 = (const float*)d_in[12];
  const float* W3 = (const float*)d_in[13];
  const float* b3 = (const float*)d_in[14];
  const float* g3 = (const float*)d_in[15];
  const float* be3 = (const float*)d_in[16];
  const float* fc1w = (const float*)d_in[17];
  const float* fc1b = (const float*)d_in[18];
  const float* fc2w = (const float*)d_in[19];
  const float* fc2b = (const float*)d_in[20];
  float* out = (float*)d_out;

  char* ws = (char*)d_ws;
  size_t off = 0;
  auto alloc = [&](size_t bytes) {
    void* p = ws + off;
    off = (off + bytes + 255) & ~(size_t)255;
    return p;
  };
  int*    ptr    = (int*)alloc((NN + 1) * sizeof(int));   // histogram (zeroed by k_init)
  int*    rowp   = (int*)alloc((NN + 1) * sizeof(int));   // final CSR row starts
  int*    pos    = (int*)alloc(NN * sizeof(int));         // placement cursors
  float*  degf   = (float*)alloc(NN * sizeof(float));
  int2*   se     = (int2*)alloc((size_t)NE * sizeof(int2));  // CSR slot -> {src node, orig edge}
  ushort* A1     = (ushort*)alloc((size_t)NN * K1 * sizeof(ushort));
  ushort* A23    = (ushort*)alloc((size_t)NN * K23 * sizeof(ushort));
  ushort* Wt1    = (ushort*)alloc((size_t)256 * K1 * sizeof(ushort));
  ushort* Wt2    = (ushort*)alloc((size_t)256 * K23 * sizeof(ushort));
  ushort* Wt3    = (ushort*)alloc((size_t)256 * K23 * sizeof(ushort));
  ushort* xb     = (ushort*)alloc((size_t)NN * CIN * sizeof(ushort));
  ushort* tmp    = (ushort*)alloc((size_t)NN * CHID * sizeof(ushort));        // bf16 pre-BN h
  unsigned char* tmp8 = (unsigned char*)alloc((size_t)NN * CHID);             // fp8 pre-BN h (L2-resident)
  float*  stats  = (float*)alloc(6 * CHID * sizeof(float));  // [layer][sum|sq][256] (zeroed by k_init)
  (void)ws_size; (void)n_in; (void)in_sizes; (void)out_size;

  float* cs1 = stats + 0 * 512, *cq1 = stats + 0 * 512 + 256;
  float* cs2 = stats + 1 * 512, *cq2 = stats + 1 * 512 + 256;
  float* cs3 = stats + 2 * 512, *cq3 = stats + 2 * 512 + 256;

  // CSR build + prep
  k_init<<<cdiv(NN + 1, 256), 256, 0, stream>>>(ptr, stats);
  k_count<<<1250, 256, 0, stream>>>(ei, ptr);
  k_scan<<<1, 1024, 0, stream>>>(ptr, rowp, pos, degf);
  k_fill<<<1250, 256, 0, stream>>>(ei, pos, se);
  k_prep<<<1250 + 1472, 256, 0, stream>>>((const float4*)x, degf, A1, xb,
                                          W1, W2, W3, Wt1, Wt2, Wt3);
  k_eag<<<NN / 4, 256, 0, stream>>>((const float4*)eattr, xb, rowp, se, A1, A23);

  dim3 ggrid(cdiv(NN, 128), CHID / 64);  // (79, 4)

  // layer 1
  k_gemm<<<ggrid, 256, 0, stream>>>(A1, Wt1, b1, degf, tmp, tmp8, cs1, cq1, K1);
  k_gbn<<<NN / 4, 256, 0, stream>>>(tmp, (const unsigned*)tmp8, cs1, cq1, g1, be1, rowp, se, degf, A23);

  // layer 2
  k_gemm<<<ggrid, 256, 0, stream>>>(A23, Wt2, b2, degf, tmp, tmp8, cs2, cq2, K23);
  k_gbn<<<NN / 4, 256, 0, stream>>>(tmp, (const unsigned*)tmp8, cs2, cq2, g2, be2, rowp, se, degf, A23);

  // layer 3
  k_gemm<<<ggrid, 256, 0, stream>>>(A23, Wt3, b3, degf, tmp, tmp8, cs3, cq3, K23);

  // fused pool + MLP head
  k_poolmlp<<<NB, 512, 0, stream>>>(tmp, cs3, cq3, g3, be3, batch, nbr,
                                    fc1w, fc1b, fc2w, fc2b, out);
}

// Round 7
// 389.972 us; speedup vs baseline: 1.0006x; 1.0006x over previous
//
#include <hip/hip_runtime.h>

#define NN 10000      // nodes
#define NE 320000     // edges (before self-loops)
#define NB 64         // graphs
#define CIN 128       // in_channels
#define CEC 64        // edge_channels
#define CHID 256      // hidden
#define CMLP 512
#define CNC 4
#define K1 (2 * CIN + CEC)    // 320
#define K23 (2 * CHID + CEC)  // 576

static __host__ int cdiv(int a, int b) { return (a + b - 1) / b; }

typedef short sfrag __attribute__((ext_vector_type(8)));   // 8 bf16 in 4 VGPRs
typedef float f4 __attribute__((ext_vector_type(4)));
typedef float f2 __attribute__((ext_vector_type(2)));

static __device__ __forceinline__ ushort f2b(float f) {
  union { float f; unsigned u; } v; v.f = f;
  unsigned r = (v.u + 0x7fffu + ((v.u >> 16) & 1u)) >> 16;
  return (ushort)r;
}
static __device__ __forceinline__ float b2f(ushort u) {
  union { unsigned u; float f; } v; v.u = ((unsigned)u) << 16;
  return v.f;
}

// ---------------- zero the per-launch accumulators (workspace is POISONED each iteration) ----------------
__global__ __launch_bounds__(256) void k_init(int* __restrict__ ptr, float* __restrict__ stats) {
  int i = blockIdx.x * 256 + threadIdx.x;
  if (i <= NN) ptr[i] = 0;
  if (i < 6 * CHID) stats[i] = 0.f;
}

// ---------------- edge-degree histogram into ptr[d+1] ----------------
__global__ __launch_bounds__(256) void k_count(const int* __restrict__ ei, int* __restrict__ ptr) {
  int e = blockIdx.x * 256 + threadIdx.x;  // 1250*256 == NE exactly
  atomicAdd(&ptr[ei[NE + e] + 1], 1);
}

// ---------------- one-block scan: ptr(histogram) -> rowp/pos/degf ----------------
#define SC 10
__global__ __launch_bounds__(1024) void k_scan(const int* __restrict__ ptr, int* __restrict__ rowp,
                                               int* __restrict__ pos, float* __restrict__ degf) {
  int t = threadIdx.x;
  int base = t * SC;
  int v[SC];
#pragma unroll
  for (int j = 0; j < SC; ++j) {
    int i = base + j;
    v[j] = (i <= NN) ? ptr[i] : 0;
  }
  int bnd;  // orig[base+SC]
  { int i = base + SC; bnd = (i <= NN) ? ptr[i] : 0; }
#pragma unroll
  for (int j = 1; j < SC; ++j) v[j] += v[j - 1];
  int tot = v[SC - 1];
  int lane = t & 63, wid = t >> 6;
  int sc = tot;
#pragma unroll
  for (int d = 1; d < 64; d <<= 1) {
    int tt = __shfl_up(sc, d);
    if (lane >= d) sc += tt;
  }
  __shared__ int ws[16];
  if (lane == 63) ws[wid] = sc;
  __syncthreads();
  int add = 0;
#pragma unroll
  for (int w2 = 0; w2 < 16; ++w2) if (w2 < wid) add += ws[w2];
  int pre = add + sc - tot;  // exclusive prefix of this thread's chunk
#pragma unroll
  for (int j = 0; j < SC; ++j) {
    int i = base + j;
    if (i > NN) break;
    int fin = pre + v[j];  // inclusive sum over orig[0..i] == CSR row start of i
    rowp[i] = fin;
    if (i < NN) {
      pos[i] = fin;
      int nxtorig = (j + 1 < SC) ? (v[j + 1] - v[j]) : bnd;
      degf[i] = (float)(nxtorig + 1);  // degree + self-loop
    }
  }
}

// ---------------- counting-sort placement: se[slot] = {src, orig-edge} (one 8B scatter) ----------------
__global__ __launch_bounds__(256) void k_fill(const int* __restrict__ ei, int* __restrict__ pos,
                                              int2* __restrict__ se) {
  int e = blockIdx.x * 256 + threadIdx.x;  // 1250*256 == NE
  int d = ei[NE + e];
  int idx = atomicAdd(&pos[d], 1);
  se[idx] = make_int2(ei[e], e);
}

// ---------------- prep: [0,20000) fp8 edge table in CSR order (random READ, sequential WRITE);
//                        [20000,21250) A1[:,0:128]=bf16(degf*x), xb=bf16(x);
//                        [21250,22722) weight transposes ----------------
__global__ __launch_bounds__(256) void k_prep(const float4* __restrict__ eattr4, const int2* __restrict__ se,
                                              unsigned char* __restrict__ eattrs8, const float4* __restrict__ x,
                                              const float* __restrict__ degf, ushort* __restrict__ A1,
                                              ushort* __restrict__ xb, const float* __restrict__ W1,
                                              const float* __restrict__ W2, const float* __restrict__ W3,
                                              ushort* __restrict__ Wt1, ushort* __restrict__ Wt2,
                                              ushort* __restrict__ Wt3) {
  int b = blockIdx.x;
  int tid = threadIdx.x;
  if (b < 20000) {
    int sp = b * 16 + (tid >> 4);       // CSR slot
    int c0 = (tid & 15) << 2;           // channel base
    int eo = se[sp].y;                  // original edge (random read, fully parallel)
    float4 v = eattr4[(size_t)eo * 16 + (tid & 15)];
    int w = __builtin_amdgcn_cvt_pk_fp8_f32(v.x, v.y, 0, false);
    w = __builtin_amdgcn_cvt_pk_fp8_f32(v.z, v.w, w, true);
    *(unsigned*)&eattrs8[(size_t)sp * CEC + c0] = (unsigned)w;
  } else if (b < 21250) {
    int gid = (b - 20000) * 256 + tid;  // NN*32 = 320000
    int node = gid >> 5;
    int c4 = (gid & 31) << 2;
    float d = degf[node];
    float4 v = x[gid];
    ushort4 o = { f2b(d * v.x), f2b(d * v.y), f2b(d * v.z), f2b(d * v.w) };
    *(ushort4*)&A1[(size_t)node * K1 + c4] = o;
    ushort4 xo = { f2b(v.x), f2b(v.y), f2b(v.z), f2b(v.w) };
    *(ushort4*)&xb[(size_t)node * CIN + c4] = xo;
  } else {
    int j = (b - 21250) * 256 + tid;  // 256*(K1+2*K23) = 376832
    const float* W; ushort* Wt; int Ktot;
    if (j < 256 * K1) { W = W1; Wt = Wt1; Ktot = K1; }
    else {
      j -= 256 * K1;
      if (j < 256 * K23) { W = W2; Wt = Wt2; Ktot = K23; }
      else { j -= 256 * K23; W = W3; Wt = Wt3; Ktot = K23; }
    }
    int n = j / Ktot;
    int k = j - n * Ktot;
    Wt[j] = f2b(W[(size_t)k * CHID + n]);
  }
}

// ---------------- fused: ea_sum (sequential fp8, 8 rows/wave-load) + 2-row-in-flight x-gather ----------------
__global__ __launch_bounds__(256) void k_eag(const unsigned char* __restrict__ eattrs8,
                                             const ushort* __restrict__ xb,
                                             const int* __restrict__ rowp, const int2* __restrict__ se,
                                             ushort* __restrict__ A1, ushort* __restrict__ A23) {
  int node = blockIdx.x * 4 + (threadIdx.x >> 6);
  int lane = threadIdx.x & 63;
  int s = rowp[node], e = rowp[node + 1];
  int nrows = e - s;

  // ea-sum: lane l holds channels 8*(l&7)..+7 of row (8g + l>>3); uint2/lane = 8 rows per wave-load.
  const int lrow = lane >> 3;
  const int lch = lane & 7;
  float a0 = 0.f, a1 = 0.f, a2 = 0.f, a3 = 0.f, a4 = 0.f, a5 = 0.f, a6 = 0.f, a7 = 0.f;
  const uint2* e8 = (const uint2*)(eattrs8 + (size_t)s * CEC);
  int full8 = nrows & ~7;
  for (int r0 = 0; r0 < full8; r0 += 8) {
    uint2 u = e8[(size_t)(r0 + lrow) * 8 + lch];
    f2 p0 = __builtin_amdgcn_cvt_pk_f32_fp8(u.x, false);
    f2 p1 = __builtin_amdgcn_cvt_pk_f32_fp8(u.x, true);
    f2 p2 = __builtin_amdgcn_cvt_pk_f32_fp8(u.y, false);
    f2 p3 = __builtin_amdgcn_cvt_pk_f32_fp8(u.y, true);
    a0 += p0.x; a1 += p0.y; a2 += p1.x; a3 += p1.y;
    a4 += p2.x; a5 += p2.y; a6 += p3.x; a7 += p3.y;
  }
  if (full8 + lrow < nrows) {  // tail (reads stay inside padded alloc)
    uint2 u = e8[(size_t)(full8 + lrow) * 8 + lch];
    f2 p0 = __builtin_amdgcn_cvt_pk_f32_fp8(u.x, false);
    f2 p1 = __builtin_amdgcn_cvt_pk_f32_fp8(u.x, true);
    f2 p2 = __builtin_amdgcn_cvt_pk_f32_fp8(u.y, false);
    f2 p3 = __builtin_amdgcn_cvt_pk_f32_fp8(u.y, true);
    a0 += p0.x; a1 += p0.y; a2 += p1.x; a3 += p1.y;
    a4 += p2.x; a5 += p2.y; a6 += p3.x; a7 += p3.y;
  }
#pragma unroll
  for (int m = 8; m < 64; m <<= 1) {
    a0 += __shfl_xor(a0, m); a1 += __shfl_xor(a1, m);
    a2 += __shfl_xor(a2, m); a3 += __shfl_xor(a3, m);
    a4 += __shfl_xor(a4, m); a5 += __shfl_xor(a5, m);
    a6 += __shfl_xor(a6, m); a7 += __shfl_xor(a7, m);
  }
  if (lane < 8) {  // +1.0 self-loop fill; lane writes channels 8*lane..+7
    ushort o[8] = { f2b(a0 + 1.f), f2b(a1 + 1.f), f2b(a2 + 1.f), f2b(a3 + 1.f),
                    f2b(a4 + 1.f), f2b(a5 + 1.f), f2b(a6 + 1.f), f2b(a7 + 1.f) };
    uint4 pk = *(const uint4*)o;
    *(uint4*)&A1[(size_t)node * K1 + 2 * CIN + lane * 8] = pk;
    *(uint4*)&A23[(size_t)node * K23 + 2 * CHID + lane * 8] = pk;
  }

  // x-gather: 2 rows in flight (wave halves), 32 lanes x ushort4 per row
  const int half = lane >> 5, l5 = lane & 31;
  float g0, g1, g2, g3;
  {
    ushort4 ow = *(const ushort4*)&xb[(size_t)node * CIN + l5 * 4];
    if (half == 0) { g0 = b2f(ow.x); g1 = b2f(ow.y); g2 = b2f(ow.z); g3 = b2f(ow.w); }
    else           { g0 = 0.f; g1 = 0.f; g2 = 0.f; g3 = 0.f; }
  }
  int myi = (lane < 32 && s + lane < e) ? se[s + lane].x : 0;
  for (int k0 = s; k0 < e; k0 += 32) {
    int rem = e - k0;
    int cur = myi;
    int nk = k0 + 32;
    if (nk < e) myi = (lane < 32 && nk + lane < e) ? se[nk + lane].x : 0;
    if (rem >= 32) {
#pragma unroll
      for (int j2 = 0; j2 < 32; j2 += 2) {
        int idx = __shfl(cur, j2 + half);
        ushort4 v = *(const ushort4*)&xb[(size_t)idx * CIN + l5 * 4];
        g0 += b2f(v.x); g1 += b2f(v.y); g2 += b2f(v.z); g3 += b2f(v.w);
      }
    } else {
#pragma unroll
      for (int j2 = 0; j2 < 32; j2 += 2) {
        if (j2 >= rem) break;  // wave-uniform
        int jj = j2 + half;
        if (jj < rem) {        // predicated only in final odd pair
          int idx = __shfl(cur, jj);
          ushort4 v = *(const ushort4*)&xb[(size_t)idx * CIN + l5 * 4];
          g0 += b2f(v.x); g1 += b2f(v.y); g2 += b2f(v.z); g3 += b2f(v.w);
        }
      }
    }
  }
  g0 += __shfl_xor(g0, 32); g1 += __shfl_xor(g1, 32);
  g2 += __shfl_xor(g2, 32); g3 += __shfl_xor(g3, 32);
  if (lane < 32) {
    ushort4 go = { f2b(g0), f2b(g1), f2b(g2), f2b(g3) };
    *(ushort4*)&A1[(size_t)node * K1 + CIN + l5 * 4] = go;
  }
}

// ---------------- layers 2/3: fused BN-apply + 2-row-in-flight gather ----------------
__global__ __launch_bounds__(256) void k_gbn(const ushort* __restrict__ tmp, const unsigned* __restrict__ t8,
                                             const float* __restrict__ colsum, const float* __restrict__ colsq,
                                             const float* __restrict__ g, const float* __restrict__ be,
                                             const int* __restrict__ rowp, const int2* __restrict__ se,
                                             const float* __restrict__ degf, ushort* __restrict__ A23) {
  int node = blockIdx.x * 4 + (threadIdx.x >> 6);
  int lane = threadIdx.x & 63;
  int c4 = lane << 2;
  float sc[4], sh[4];
#pragma unroll
  for (int j = 0; j < 4; ++j) {
    int c = c4 + j;
    float mu = colsum[c] * (1.f / (float)NN);
    float var = colsq[c] * (1.f / (float)NN) - mu * mu;
    float inv = rsqrtf(var + 1e-5f);
    sc[j] = g[c] * inv;
    sh[j] = be[c] - mu * sc[j];
  }
  // own row (bf16 full-precision path): BN+relu, write degf-scaled self panel
  ushort4 tv = *(const ushort4*)&tmp[(size_t)node * CHID + c4];
  float o0 = fmaxf(fmaf(b2f(tv.x), sc[0], sh[0]), 0.f);
  float o1 = fmaxf(fmaf(b2f(tv.y), sc[1], sh[1]), 0.f);
  float o2 = fmaxf(fmaf(b2f(tv.z), sc[2], sh[2]), 0.f);
  float o3 = fmaxf(fmaf(b2f(tv.w), sc[3], sh[3]), 0.f);
  float d = degf[node];
  ushort4 ao = { f2b(d * o0), f2b(d * o1), f2b(d * o2), f2b(d * o3) };
  *(ushort4*)&A23[(size_t)node * K23 + c4] = ao;

  // gather: 2 rows in flight (wave halves), 32 lanes x uint2 (8 fp8 ch) per row
  const int half = lane >> 5, l5 = lane & 31;
  const int c8 = l5 << 3;
  float s8[8], h8[8];
#pragma unroll
  for (int k = 0; k < 8; ++k) {
    int c = c8 + k;
    float mu = colsum[c] * (1.f / (float)NN);
    float var = colsq[c] * (1.f / (float)NN) - mu * mu;
    float inv = rsqrtf(var + 1e-5f);
    s8[k] = g[c] * inv;
    h8[k] = be[c] - mu * s8[k];
  }
  // seed with own h_node channels c8..c8+7 (counted once, half 0 only)
  float a[8];
  a[0] = __shfl(o0, 2 * l5);     a[1] = __shfl(o1, 2 * l5);
  a[2] = __shfl(o2, 2 * l5);     a[3] = __shfl(o3, 2 * l5);
  a[4] = __shfl(o0, 2 * l5 + 1); a[5] = __shfl(o1, 2 * l5 + 1);
  a[6] = __shfl(o2, 2 * l5 + 1); a[7] = __shfl(o3, 2 * l5 + 1);
  if (half) {
#pragma unroll
    for (int k = 0; k < 8; ++k) a[k] = 0.f;
  }
  int s = rowp[node], e = rowp[node + 1];
  int myi = (lane < 32 && s + lane < e) ? se[s + lane].x : 0;
  for (int k0 = s; k0 < e; k0 += 32) {
    int rem = e - k0;
    int cur = myi;
    int nk = k0 + 32;
    if (nk < e) myi = (lane < 32 && nk + lane < e) ? se[nk + lane].x : 0;
    if (rem >= 32) {
#pragma unroll
      for (int j2 = 0; j2 < 32; j2 += 2) {
        int idx = __shfl(cur, j2 + half);
        uint2 u = *(const uint2*)&t8[(size_t)idx * 64 + l5 * 2];
        f2 p0 = __builtin_amdgcn_cvt_pk_f32_fp8(u.x, false);
        f2 p1 = __builtin_amdgcn_cvt_pk_f32_fp8(u.x, true);
        f2 p2 = __builtin_amdgcn_cvt_pk_f32_fp8(u.y, false);
        f2 p3 = __builtin_amdgcn_cvt_pk_f32_fp8(u.y, true);
        a[0] += fmaxf(fmaf(p0.x, s8[0], h8[0]), 0.f);
        a[1] += fmaxf(fmaf(p0.y, s8[1], h8[1]), 0.f);
        a[2] += fmaxf(fmaf(p1.x, s8[2], h8[2]), 0.f);
        a[3] += fmaxf(fmaf(p1.y, s8[3], h8[3]), 0.f);
        a[4] += fmaxf(fmaf(p2.x, s8[4], h8[4]), 0.f);
        a[5] += fmaxf(fmaf(p2.y, s8[5], h8[5]), 0.f);
        a[6] += fmaxf(fmaf(p3.x, s8[6], h8[6]), 0.f);
        a[7] += fmaxf(fmaf(p3.y, s8[7], h8[7]), 0.f);
      }
    } else {
#pragma unroll
      for (int j2 = 0; j2 < 32; j2 += 2) {
        if (j2 >= rem) break;  // wave-uniform
        int jj = j2 + half;
        if (jj < rem) {        // predicated only in final odd pair
          int idx = __shfl(cur, jj);
          uint2 u = *(const uint2*)&t8[(size_t)idx * 64 + l5 * 2];
          f2 p0 = __builtin_amdgcn_cvt_pk_f32_fp8(u.x, false);
          f2 p1 = __builtin_amdgcn_cvt_pk_f32_fp8(u.x, true);
          f2 p2 = __builtin_amdgcn_cvt_pk_f32_fp8(u.y, false);
          f2 p3 = __builtin_amdgcn_cvt_pk_f32_fp8(u.y, true);
          a[0] += fmaxf(fmaf(p0.x, s8[0], h8[0]), 0.f);
          a[1] += fmaxf(fmaf(p0.y, s8[1], h8[1]), 0.f);
          a[2] += fmaxf(fmaf(p1.x, s8[2], h8[2]), 0.f);
          a[3] += fmaxf(fmaf(p1.y, s8[3], h8[3]), 0.f);
          a[4] += fmaxf(fmaf(p2.x, s8[4], h8[4]), 0.f);
          a[5] += fmaxf(fmaf(p2.y, s8[5], h8[5]), 0.f);
          a[6] += fmaxf(fmaf(p3.x, s8[6], h8[6]), 0.f);
          a[7] += fmaxf(fmaf(p3.y, s8[7], h8[7]), 0.f);
        }
      }
    }
  }
#pragma unroll
  for (int k = 0; k < 8; ++k) a[k] += __shfl_xor(a[k], 32);
  if (lane < 32) {
    ushort o8[8] = { f2b(a[0]), f2b(a[1]), f2b(a[2]), f2b(a[3]),
                     f2b(a[4]), f2b(a[5]), f2b(a[6]), f2b(a[7]) };
    *(uint4*)&A23[(size_t)node * K23 + CHID + c8] = *(const uint4*)o8;
  }
}

// ---------------- MFMA GEMM (128x64 tile, register-prefetch dbuf, R0-exact) ----------------
__global__ __launch_bounds__(256) void k_gemm(const ushort* __restrict__ Ag, const ushort* __restrict__ Wt,
                                              const float* __restrict__ bias, const float* __restrict__ degf,
                                              ushort* __restrict__ outb, unsigned char* __restrict__ out8,
                                              float* __restrict__ colsum, float* __restrict__ colsq, int Ktot) {
  __shared__ ushort As[128 * 40];  // 128 rows x 32 k, stride 40
  __shared__ ushort Bs[64 * 40];   // 64 n x 32 k
  const int bm = blockIdx.x * 128;
  const int bn = blockIdx.y * 64;
  const int tid = threadIdx.x;
  const int w = tid >> 6;
  const int lane = tid & 63;
  const int ln = lane & 15;
  const int quad = lane >> 4;

  f4 acc[2][4];
#pragma unroll
  for (int mf = 0; mf < 2; ++mf)
#pragma unroll
    for (int nf = 0; nf < 4; ++nf) acc[mf][nf] = (f4){0.f, 0.f, 0.f, 0.f};

  const int rA = tid >> 1;
  const int hk = (tid & 1) << 4;  // 0 or 16
  const int rowA = bm + rA;
  const int nB = tid >> 2;
  const int kq = (tid & 3) << 3;  // 0,8,16,24
  const ushort* ap = Ag + (size_t)min(rowA, NN - 1) * Ktot + hk;
  const ushort* bp = Wt + (size_t)(bn + nB) * Ktot + kq;

  const int iters = Ktot >> 5;
  uint4 av0 = ((const uint4*)ap)[0];
  uint4 av1 = ((const uint4*)ap)[1];
  uint4 bv = *(const uint4*)bp;
  for (int it = 0; it < iters; ++it) {
    *(uint4*)&As[rA * 40 + hk] = av0;
    *(uint4*)&As[rA * 40 + hk + 8] = av1;
    *(uint4*)&Bs[nB * 40 + kq] = bv;
    __syncthreads();
    if (it + 1 < iters) {  // prefetch next K-tile while MFMAs consume LDS
      const ushort* apn = ap + (it + 1) * 32;
      av0 = ((const uint4*)apn)[0];
      av1 = ((const uint4*)apn)[1];
      bv = *(const uint4*)(bp + (it + 1) * 32);
    }
    sfrag a0 = *(const sfrag*)&As[(w * 32 + ln) * 40 + quad * 8];
    sfrag a1 = *(const sfrag*)&As[(w * 32 + 16 + ln) * 40 + quad * 8];
#pragma unroll
    for (int nf = 0; nf < 4; ++nf) {
      sfrag b = *(const sfrag*)&Bs[(nf * 16 + ln) * 40 + quad * 8];
      acc[0][nf] = __builtin_amdgcn_mfma_f32_16x16x32_bf16(a0, b, acc[0][nf], 0, 0, 0);
      acc[1][nf] = __builtin_amdgcn_mfma_f32_16x16x32_bf16(a1, b, acc[1][nf], 0, 0, 0);
    }
    __syncthreads();
  }

  float bcol[4];
#pragma unroll
  for (int nf = 0; nf < 4; ++nf) bcol[nf] = bias[bn + nf * 16 + ln];
  float ssum[4] = {0.f, 0.f, 0.f, 0.f}, sqq[4] = {0.f, 0.f, 0.f, 0.f};
#pragma unroll
  for (int mf = 0; mf < 2; ++mf) {
    int rbase = bm + w * 32 + mf * 16 + quad * 4;
#pragma unroll
    for (int r = 0; r < 4; ++r) {
      int row = rbase + r;
      bool valid = row < NN;
      float d = valid ? degf[row] : 0.f;
#pragma unroll
      for (int nf = 0; nf < 4; ++nf) {
        float v = fmaxf(acc[mf][nf][r] + d * bcol[nf], 0.f);
        if (valid) {
          size_t oidx = (size_t)row * CHID + bn + nf * 16 + ln;
          outb[oidx] = f2b(v);
          int enc = __builtin_amdgcn_cvt_pk_fp8_f32(v, v, 0, false);
          out8[oidx] = (unsigned char)enc;
          ssum[nf] += v;
          sqq[nf] += v * v;
        }
      }
    }
  }
#pragma unroll
  for (int nf = 0; nf < 4; ++nf) {
    float s = ssum[nf], q = sqq[nf];
    s += __shfl_xor(s, 16); s += __shfl_xor(s, 32);
    q += __shfl_xor(q, 16); q += __shfl_xor(q, 32);
    if (quad == 0) {
      atomicAdd(&colsum[bn + nf * 16 + ln], s);
      atomicAdd(&colsq[bn + nf * 16 + ln], q);
    }
  }
}

// ---------------- fused: per-graph BN+relu pooling + MLP head (one block per graph) ----------------
__global__ __launch_bounds__(512) void k_poolmlp(const ushort* __restrict__ t3, const float* __restrict__ colsum,
                                                 const float* __restrict__ colsq, const float* __restrict__ g3,
                                                 const float* __restrict__ be3, const int* __restrict__ batch,
                                                 const float* __restrict__ nb, const float* __restrict__ w1,
                                                 const float* __restrict__ b1, const float* __restrict__ w2,
                                                 const float* __restrict__ b2, float* __restrict__ out) {
  int g = blockIdx.x;
  int t = threadIdx.x;
  __shared__ int sgs, sge;
  __shared__ f4 pq[8][64];                 // 8 row-offset partials x 64 col-groups
  __shared__ float zin[CHID + 1 + CIN];    // 385
  __shared__ float red[8];
  if (t == 0) { sgs = NN; sge = 0; }
  __syncthreads();
  for (int i = t; i < NN; i += 512) {
    if (batch[i] == g) { atomicMin(&sgs, i); atomicMax(&sge, i + 1); }
  }
  __syncthreads();
  int gs = sgs, ge = sge;
  int cnt = (ge > gs) ? (ge - gs) : 0;

  int cg = t & 63, off = t >> 6;
  int c0 = cg << 2;
  float scv[4], shv[4];
#pragma unroll
  for (int j = 0; j < 4; ++j) {
    int c = c0 + j;
    float mu = colsum[c] * (1.f / (float)NN);
    float var = colsq[c] * (1.f / (float)NN) - mu * mu;
    float inv = rsqrtf(var + 1e-5f);
    scv[j] = g3[c] * inv;
    shv[j] = be3[c] - mu * scv[j];
  }
  f4 acc = (f4){0.f, 0.f, 0.f, 0.f};
  for (int r = gs + off; r < ge; r += 8) {
    ushort4 tv = *(const ushort4*)&t3[(size_t)r * CHID + c0];
    acc.x += fmaxf(fmaf(b2f(tv.x), scv[0], shv[0]), 0.f);
    acc.y += fmaxf(fmaf(b2f(tv.y), scv[1], shv[1]), 0.f);
    acc.z += fmaxf(fmaf(b2f(tv.z), scv[2], shv[2]), 0.f);
    acc.w += fmaxf(fmaf(b2f(tv.w), scv[3], shv[3]), 0.f);
  }
  pq[off][cg] = acc;
  __syncthreads();
  if (t < CHID) {
    float s = 0.f;
#pragma unroll
    for (int o = 0; o < 8; ++o) s += ((const float*)&pq[o][t >> 2])[t & 3];
    zin[t] = s;
  } else if (t == CHID) zin[CHID] = (float)cnt * 0.025f;  // / MAX_SIZE(40)
  else if (t < CHID + 1 + CIN) zin[t] = nb[g * CIN + (t - CHID - 1)];
  __syncthreads();

  float acc1 = b1[t];
  for (int k = 0; k < CHID + 1 + CIN; ++k) acc1 = fmaf(zin[k], w1[k * CMLP + t], acc1);
  float z = fmaxf(acc1, 0.f);
  int wid = t >> 6, wl = t & 63;
#pragma unroll
  for (int n = 0; n < CNC; ++n) {
    float part = z * w2[t * CNC + n];
#pragma unroll
    for (int d = 1; d < 64; d <<= 1) part += __shfl_xor(part, d);
    if (wl == 0) red[wid] = part;
    __syncthreads();
    if (t == 0) {
      float tot = 0.f;
#pragma unroll
      for (int i = 0; i < 8; ++i) tot += red[i];
      out[g * CNC + n] = tot + b2[n];
    }
    __syncthreads();
  }
}

// ---------------- launch ----------------

extern "C" void kernel_launch(void* const* d_in, const int* in_sizes, int n_in,
                              void* d_out, int out_size, void* d_ws, size_t ws_size,
                              hipStream_t stream) {
  const float* x     = (const float*)d_in[0];
  const int*   ei    = (const int*)d_in[1];
  const float* eattr = (const float*)d_in[2];
  const int*   batch = (const int*)d_in[3];
  const float* nbr   = (const float*)d_in[4];
  const float* W1 = (const float*)d_in[5];
  const float* b1 = (const float*)d_in[6];
  const float* g1 = (const float*)d_in[7];
  const float* be1 = (const float*)d_in[8];
  const float* W2 = (const float*)d_in[9];
  const float* b2 = (const float*)d_in[10];
  const float* g2 = (const float*)d_in[11];
  const float* be2 = (const float*)d_in[12];
  const float* W3 = (const float*)d_in[13];
  const float* b3 = (const float*)d_in[14];
  const float* g3 = (const float*)d_in[15];
  const float* be3 = (const float*)d_in[16];
  const float* fc1w = (const float*)d_in[17];
  const float* fc1b = (const float*)d_in[18];
  const float* fc2w = (const float*)d_in[19];
  const float* fc2b = (const float*)d_in[20];
  float* out = (float*)d_out;

  char* ws = (char*)d_ws;
  size_t off = 0;
  auto alloc = [&](size_t bytes) {
    void* p = ws + off;
    off = (off + bytes + 255) & ~(size_t)255;
    return p;
  };
  int*    ptr    = (int*)alloc((NN + 1) * sizeof(int));   // histogram (zeroed by k_init)
  int*    rowp   = (int*)alloc((NN + 1) * sizeof(int));   // final CSR row starts
  int*    pos    = (int*)alloc(NN * sizeof(int));         // placement cursors
  float*  degf   = (float*)alloc(NN * sizeof(float));
  int2*   se     = (int2*)alloc((size_t)NE * sizeof(int2));  // CSR slot -> {src node, orig edge}
  unsigned char* eattrs8 = (unsigned char*)alloc((size_t)(NE + 8) * CEC);  // 20.5 MB fp8 CSR-ordered
  ushort* A1     = (ushort*)alloc((size_t)NN * K1 * sizeof(ushort));
  ushort* A23    = (ushort*)alloc((size_t)NN * K23 * sizeof(ushort));
  ushort* Wt1    = (ushort*)alloc((size_t)256 * K1 * sizeof(ushort));
  ushort* Wt2    = (ushort*)alloc((size_t)256 * K23 * sizeof(ushort));
  ushort* Wt3    = (ushort*)alloc((size_t)256 * K23 * sizeof(ushort));
  ushort* xb     = (ushort*)alloc((size_t)NN * CIN * sizeof(ushort));
  ushort* tmp    = (ushort*)alloc((size_t)NN * CHID * sizeof(ushort));        // bf16 pre-BN h
  unsigned char* tmp8 = (unsigned char*)alloc((size_t)NN * CHID);             // fp8 pre-BN h (L2-resident)
  float*  stats  = (float*)alloc(6 * CHID * sizeof(float));  // [layer][sum|sq][256] (zeroed by k_init)
  (void)ws_size; (void)n_in; (void)in_sizes; (void)out_size;

  float* cs1 = stats + 0 * 512, *cq1 = stats + 0 * 512 + 256;
  float* cs2 = stats + 1 * 512, *cq2 = stats + 1 * 512 + 256;
  float* cs3 = stats + 2 * 512, *cq3 = stats + 2 * 512 + 256;

  // CSR build + prep
  k_init<<<cdiv(NN + 1, 256), 256, 0, stream>>>(ptr, stats);
  k_count<<<1250, 256, 0, stream>>>(ei, ptr);
  k_scan<<<1, 1024, 0, stream>>>(ptr, rowp, pos, degf);
  k_fill<<<1250, 256, 0, stream>>>(ei, pos, se);
  k_prep<<<20000 + 1250 + 1472, 256, 0, stream>>>((const float4*)eattr, se, eattrs8,
                                                  (const float4*)x, degf, A1, xb,
                                                  W1, W2, W3, Wt1, Wt2, Wt3);
  k_eag<<<NN / 4, 256, 0, stream>>>(eattrs8, xb, rowp, se, A1, A23);

  dim3 ggrid(cdiv(NN, 128), CHID / 64);  // (79, 4)

  // layer 1
  k_gemm<<<ggrid, 256, 0, stream>>>(A1, Wt1, b1, degf, tmp, tmp8, cs1, cq1, K1);
  k_gbn<<<NN / 4, 256, 0, stream>>>(tmp, (const unsigned*)tmp8, cs1, cq1, g1, be1, rowp, se, degf, A23);

  // layer 2
  k_gemm<<<ggrid, 256, 0, stream>>>(A23, Wt2, b2, degf, tmp, tmp8, cs2, cq2, K23);
  k_gbn<<<NN / 4, 256, 0, stream>>>(tmp, (const unsigned*)tmp8, cs2, cq2, g2, be2, rowp, se, degf, A23);

  // layer 3
  k_gemm<<<ggrid, 256, 0, stream>>>(A23, Wt3, b3, degf, tmp, tmp8, cs3, cq3, K23);

  // fused pool + MLP head
  k_poolmlp<<<NB, 512, 0, stream>>>(tmp, cs3, cq3, g3, be3, batch, nbr,
                                    fc1w, fc1b, fc2w, fc2b, out);
}

// Round 8
// 376.374 us; speedup vs baseline: 1.0368x; 1.0361x over previous
//
#include <hip/hip_runtime.h>

#define NN 10000      // nodes
#define NE 320000     // edges (before self-loops)
#define NB 64         // graphs
#define CIN 128       // in_channels
#define CEC 64        // edge_channels
#define CHID 256      // hidden
#define CMLP 512
#define CNC 4
#define K1 (2 * CIN + CEC)    // 320
#define K23 (2 * CHID + CEC)  // 576

static __host__ int cdiv(int a, int b) { return (a + b - 1) / b; }

typedef short sfrag __attribute__((ext_vector_type(8)));   // 8 bf16 in 4 VGPRs
typedef float f4 __attribute__((ext_vector_type(4)));
typedef float f2 __attribute__((ext_vector_type(2)));

static __device__ __forceinline__ ushort f2b(float f) {
  union { float f; unsigned u; } v; v.f = f;
  unsigned r = (v.u + 0x7fffu + ((v.u >> 16) & 1u)) >> 16;
  return (ushort)r;
}
static __device__ __forceinline__ float b2f(ushort u) {
  union { unsigned u; float f; } v; v.u = ((unsigned)u) << 16;
  return v.f;
}

// ---------------- init + dependency-free prep (zero accumulators, xb=bf16(x), weight transposes) ----------------
// [0,41): zero ptr/stats; [41,1291): xb; [1291,2763): Wt1/Wt2/Wt3
__global__ __launch_bounds__(256) void k_init(int* __restrict__ ptr, float* __restrict__ stats,
                                              const float4* __restrict__ x, ushort* __restrict__ xb,
                                              const float* __restrict__ W1, const float* __restrict__ W2,
                                              const float* __restrict__ W3, ushort* __restrict__ Wt1,
                                              ushort* __restrict__ Wt2, ushort* __restrict__ Wt3) {
  int b = blockIdx.x;
  int tid = threadIdx.x;
  if (b < 41) {
    int i = b * 256 + tid;
    if (i <= NN) ptr[i] = 0;
    if (i < 6 * CHID) stats[i] = 0.f;
  } else if (b < 1291) {
    int gid = (b - 41) * 256 + tid;  // NN*32 = 320000
    int node = gid >> 5;
    int c4 = (gid & 31) << 2;
    float4 v = x[gid];
    ushort4 xo = { f2b(v.x), f2b(v.y), f2b(v.z), f2b(v.w) };
    *(ushort4*)&xb[(size_t)node * CIN + c4] = xo;
  } else {
    int j = (b - 1291) * 256 + tid;  // 256*(K1+2*K23) = 376832
    const float* W; ushort* Wt; int Ktot;
    if (j < 256 * K1) { W = W1; Wt = Wt1; Ktot = K1; }
    else {
      j -= 256 * K1;
      if (j < 256 * K23) { W = W2; Wt = Wt2; Ktot = K23; }
      else { j -= 256 * K23; W = W3; Wt = Wt3; Ktot = K23; }
    }
    int n = j / Ktot;
    int k = j - n * Ktot;
    Wt[j] = f2b(W[(size_t)k * CHID + n]);
  }
}

// ---------------- edge-degree histogram into ptr[d+1] ----------------
__global__ __launch_bounds__(256) void k_count(const int* __restrict__ ei, int* __restrict__ ptr) {
  int e = blockIdx.x * 256 + threadIdx.x;  // 1250*256 == NE exactly
  atomicAdd(&ptr[ei[NE + e] + 1], 1);
}

// ---------------- one-block scan: ptr(histogram) -> rowp/pos/degf ----------------
#define SC 10
__global__ __launch_bounds__(1024) void k_scan(const int* __restrict__ ptr, int* __restrict__ rowp,
                                               int* __restrict__ pos, float* __restrict__ degf) {
  int t = threadIdx.x;
  int base = t * SC;
  int v[SC];
#pragma unroll
  for (int j = 0; j < SC; ++j) {
    int i = base + j;
    v[j] = (i <= NN) ? ptr[i] : 0;
  }
  int bnd;  // orig[base+SC]
  { int i = base + SC; bnd = (i <= NN) ? ptr[i] : 0; }
#pragma unroll
  for (int j = 1; j < SC; ++j) v[j] += v[j - 1];
  int tot = v[SC - 1];
  int lane = t & 63, wid = t >> 6;
  int sc = tot;
#pragma unroll
  for (int d = 1; d < 64; d <<= 1) {
    int tt = __shfl_up(sc, d);
    if (lane >= d) sc += tt;
  }
  __shared__ int ws[16];
  if (lane == 63) ws[wid] = sc;
  __syncthreads();
  int add = 0;
#pragma unroll
  for (int w2 = 0; w2 < 16; ++w2) if (w2 < wid) add += ws[w2];
  int pre = add + sc - tot;  // exclusive prefix of this thread's chunk
#pragma unroll
  for (int j = 0; j < SC; ++j) {
    int i = base + j;
    if (i > NN) break;
    int fin = pre + v[j];  // inclusive sum over orig[0..i] == CSR row start of i
    rowp[i] = fin;
    if (i < NN) {
      pos[i] = fin;
      int nxtorig = (j + 1 < SC) ? (v[j + 1] - v[j]) : bnd;
      degf[i] = (float)(nxtorig + 1);  // degree + self-loop
    }
  }
}

// ---------------- merged counting-sort placement + fp8 permute ----------------
// 16 threads/edge: leader lane atomicAdds the slot + writes srcs, broadcasts slot via shfl,
// group converts the 64-ch fp32 row to fp8 and writes it at the CSR slot (64B row).
__global__ __launch_bounds__(256) void k_fillperm(const int* __restrict__ ei, int* __restrict__ pos,
                                                  int* __restrict__ srcs, const float4* __restrict__ eattr4,
                                                  unsigned char* __restrict__ eattrs8) {
  int tid = threadIdx.x;
  int e = blockIdx.x * 16 + (tid >> 4);   // 20000*16 == NE
  int q = tid & 15;
  int lane = tid & 63;
  int idx = 0;
  if (q == 0) {
    idx = atomicAdd(&pos[ei[NE + e]], 1);
    srcs[idx] = ei[e];
  }
  idx = __shfl(idx, lane & 48);           // broadcast from 16-group leader
  float4 v = eattr4[(size_t)e * 16 + q];
  int w = __builtin_amdgcn_cvt_pk_fp8_f32(v.x, v.y, 0, false);
  w = __builtin_amdgcn_cvt_pk_fp8_f32(v.z, v.w, w, true);
  *(unsigned*)&eattrs8[(size_t)idx * CEC + (q << 2)] = (unsigned)w;
}

// ---------------- fused: A1 panel0 (degf*x) + ea_sum (fp8, 8 rows/wave-load) + layer-1 x-gather ----------------
__global__ __launch_bounds__(256) void k_eag(const unsigned char* __restrict__ eattrs8,
                                             const float* __restrict__ x, const float* __restrict__ degf,
                                             const ushort* __restrict__ xb,
                                             const int* __restrict__ rowp, const int* __restrict__ srcs,
                                             ushort* __restrict__ A1, ushort* __restrict__ A23) {
  int node = blockIdx.x * 4 + (threadIdx.x >> 6);
  int lane = threadIdx.x & 63;
  int s = rowp[node], e = rowp[node + 1];
  int nrows = e - s;

  // panel 0: A1[node, 0:128] = bf16(degf * x)  (bit-identical to R0's prep math)
  {
    float d = degf[node];
    float2 xv = ((const float2*)x)[(size_t)node * 64 + lane];
    ushort2 p0 = { f2b(d * xv.x), f2b(d * xv.y) };
    *(ushort2*)&A1[(size_t)node * K1 + lane * 2] = p0;
  }

  // ea-sum: lane l holds channels 8*(l&7)..+7 of row (8g + l>>3); uint2/lane = 8 rows per wave-load.
  const int lrow = lane >> 3;   // 0..7
  const int lch = lane & 7;     // channel-group
  float a0 = 0.f, a1 = 0.f, a2 = 0.f, a3 = 0.f, a4 = 0.f, a5 = 0.f, a6 = 0.f, a7 = 0.f;
  const uint2* e8 = (const uint2*)(eattrs8 + (size_t)s * CEC);
  int full8 = nrows & ~7;
  for (int r0 = 0; r0 < full8; r0 += 8) {
    uint2 u = e8[(size_t)(r0 + lrow) * 8 + lch];
    f2 p0 = __builtin_amdgcn_cvt_pk_f32_fp8(u.x, false);
    f2 p1 = __builtin_amdgcn_cvt_pk_f32_fp8(u.x, true);
    f2 p2 = __builtin_amdgcn_cvt_pk_f32_fp8(u.y, false);
    f2 p3 = __builtin_amdgcn_cvt_pk_f32_fp8(u.y, true);
    a0 += p0.x; a1 += p0.y; a2 += p1.x; a3 += p1.y;
    a4 += p2.x; a5 += p2.y; a6 += p3.x; a7 += p3.y;
  }
  if (full8 + lrow < nrows) {  // tail (reads stay inside padded alloc)
    uint2 u = e8[(size_t)(full8 + lrow) * 8 + lch];
    f2 p0 = __builtin_amdgcn_cvt_pk_f32_fp8(u.x, false);
    f2 p1 = __builtin_amdgcn_cvt_pk_f32_fp8(u.x, true);
    f2 p2 = __builtin_amdgcn_cvt_pk_f32_fp8(u.y, false);
    f2 p3 = __builtin_amdgcn_cvt_pk_f32_fp8(u.y, true);
    a0 += p0.x; a1 += p0.y; a2 += p1.x; a3 += p1.y;
    a4 += p2.x; a5 += p2.y; a6 += p3.x; a7 += p3.y;
  }
#pragma unroll
  for (int m = 8; m < 64; m <<= 1) {
    a0 += __shfl_xor(a0, m); a1 += __shfl_xor(a1, m);
    a2 += __shfl_xor(a2, m); a3 += __shfl_xor(a3, m);
    a4 += __shfl_xor(a4, m); a5 += __shfl_xor(a5, m);
    a6 += __shfl_xor(a6, m); a7 += __shfl_xor(a7, m);
  }
  if (lane < 8) {  // +1.0 self-loop fill; lane writes channels 8*lane..+7
    ushort o[8] = { f2b(a0 + 1.f), f2b(a1 + 1.f), f2b(a2 + 1.f), f2b(a3 + 1.f),
                    f2b(a4 + 1.f), f2b(a5 + 1.f), f2b(a6 + 1.f), f2b(a7 + 1.f) };
    uint4 pk = *(const uint4*)o;
    *(uint4*)&A1[(size_t)node * K1 + 2 * CIN + lane * 8] = pk;
    *(uint4*)&A23[(size_t)node * K23 + 2 * CHID + lane * 8] = pk;
  }

  // layer-1 gather: 32-wide pipelined chunks, uniform-break tail (R5-proven loop)
  ushort2 own = *(const ushort2*)&xb[(size_t)node * CIN + lane * 2];
  float gx = b2f(own.x), gy = b2f(own.y);
  int myi = (lane < 32 && s + lane < e) ? srcs[s + lane] : 0;
  for (int k0 = s; k0 < e; k0 += 32) {
    int rem = e - k0;
    int cur = myi;
    int nk = k0 + 32;
    if (nk < e) myi = (lane < 32 && nk + lane < e) ? srcs[nk + lane] : 0;
    if (rem >= 32) {
#pragma unroll
      for (int j = 0; j < 32; ++j) {
        int idx = __shfl(cur, j);
        ushort2 v = *(const ushort2*)&xb[(size_t)idx * CIN + lane * 2];
        gx += b2f(v.x); gy += b2f(v.y);
      }
    } else {
#pragma unroll
      for (int j = 0; j < 32; ++j) {
        if (j >= rem) break;  // wave-uniform: no load issued past rem
        int idx = __shfl(cur, j);
        ushort2 v = *(const ushort2*)&xb[(size_t)idx * CIN + lane * 2];
        gx += b2f(v.x); gy += b2f(v.y);
      }
    }
  }
  ushort2 go = { f2b(gx), f2b(gy) };
  *(ushort2*)&A1[(size_t)node * K1 + CIN + lane * 2] = go;
}

// ---------------- layers 2/3: fused BN-apply + gather (R5-proven) ----------------
__global__ __launch_bounds__(256) void k_gbn(const ushort* __restrict__ tmp, const unsigned* __restrict__ t8,
                                             const float* __restrict__ colsum, const float* __restrict__ colsq,
                                             const float* __restrict__ g, const float* __restrict__ be,
                                             const int* __restrict__ rowp, const int* __restrict__ srcs,
                                             const float* __restrict__ degf, ushort* __restrict__ A23) {
  int node = blockIdx.x * 4 + (threadIdx.x >> 6);
  int lane = threadIdx.x & 63;
  int c4 = lane << 2;
  float sc[4], sh[4];
#pragma unroll
  for (int j = 0; j < 4; ++j) {
    int c = c4 + j;
    float mu = colsum[c] * (1.f / (float)NN);
    float var = colsq[c] * (1.f / (float)NN) - mu * mu;
    float inv = rsqrtf(var + 1e-5f);
    sc[j] = g[c] * inv;
    sh[j] = be[c] - mu * sc[j];
  }
  ushort4 tv = *(const ushort4*)&tmp[(size_t)node * CHID + c4];
  float o0 = fmaxf(fmaf(b2f(tv.x), sc[0], sh[0]), 0.f);
  float o1 = fmaxf(fmaf(b2f(tv.y), sc[1], sh[1]), 0.f);
  float o2 = fmaxf(fmaf(b2f(tv.z), sc[2], sh[2]), 0.f);
  float o3 = fmaxf(fmaf(b2f(tv.w), sc[3], sh[3]), 0.f);
  float d = degf[node];
  ushort4 ao = { f2b(d * o0), f2b(d * o1), f2b(d * o2), f2b(d * o3) };
  *(ushort4*)&A23[(size_t)node * K23 + c4] = ao;

  float ax = o0, ay = o1, az = o2, aw = o3;
  int s = rowp[node], e = rowp[node + 1];
  int myi = (lane < 32 && s + lane < e) ? srcs[s + lane] : 0;
  for (int k0 = s; k0 < e; k0 += 32) {
    int rem = e - k0;
    int cur = myi;
    int nk = k0 + 32;
    if (nk < e) myi = (lane < 32 && nk + lane < e) ? srcs[nk + lane] : 0;
    if (rem >= 32) {
#pragma unroll
      for (int j = 0; j < 32; ++j) {
        int idx = __shfl(cur, j);
        unsigned u = t8[(size_t)idx * 64 + lane];
        f2 lo = __builtin_amdgcn_cvt_pk_f32_fp8(u, false);
        f2 hi = __builtin_amdgcn_cvt_pk_f32_fp8(u, true);
        ax += fmaxf(fmaf(lo.x, sc[0], sh[0]), 0.f);
        ay += fmaxf(fmaf(lo.y, sc[1], sh[1]), 0.f);
        az += fmaxf(fmaf(hi.x, sc[2], sh[2]), 0.f);
        aw += fmaxf(fmaf(hi.y, sc[3], sh[3]), 0.f);
      }
    } else {
#pragma unroll
      for (int j = 0; j < 32; ++j) {
        if (j >= rem) break;  // wave-uniform: no load issued past rem
        int idx = __shfl(cur, j);
        unsigned u = t8[(size_t)idx * 64 + lane];
        f2 lo = __builtin_amdgcn_cvt_pk_f32_fp8(u, false);
        f2 hi = __builtin_amdgcn_cvt_pk_f32_fp8(u, true);
        ax += fmaxf(fmaf(lo.x, sc[0], sh[0]), 0.f);
        ay += fmaxf(fmaf(lo.y, sc[1], sh[1]), 0.f);
        az += fmaxf(fmaf(hi.x, sc[2], sh[2]), 0.f);
        aw += fmaxf(fmaf(hi.y, sc[3], sh[3]), 0.f);
      }
    }
  }
  ushort4 o = { f2b(ax), f2b(ay), f2b(az), f2b(aw) };
  *(ushort4*)&A23[(size_t)node * K23 + CHID + c4] = o;
}

// ---------------- MFMA GEMM (128x64 tile, register-prefetch dbuf, R0-exact) ----------------
__global__ __launch_bounds__(256) void k_gemm(const ushort* __restrict__ Ag, const ushort* __restrict__ Wt,
                                              const float* __restrict__ bias, const float* __restrict__ degf,
                                              ushort* __restrict__ outb, unsigned char* __restrict__ out8,
                                              float* __restrict__ colsum, float* __restrict__ colsq, int Ktot) {
  __shared__ ushort As[128 * 40];  // 128 rows x 32 k, stride 40
  __shared__ ushort Bs[64 * 40];   // 64 n x 32 k
  const int bm = blockIdx.x * 128;
  const int bn = blockIdx.y * 64;
  const int tid = threadIdx.x;
  const int w = tid >> 6;
  const int lane = tid & 63;
  const int ln = lane & 15;
  const int quad = lane >> 4;

  f4 acc[2][4];
#pragma unroll
  for (int mf = 0; mf < 2; ++mf)
#pragma unroll
    for (int nf = 0; nf < 4; ++nf) acc[mf][nf] = (f4){0.f, 0.f, 0.f, 0.f};

  const int rA = tid >> 1;
  const int hk = (tid & 1) << 4;  // 0 or 16
  const int rowA = bm + rA;
  const int nB = tid >> 2;
  const int kq = (tid & 3) << 3;  // 0,8,16,24
  const ushort* ap = Ag + (size_t)min(rowA, NN - 1) * Ktot + hk;
  const ushort* bp = Wt + (size_t)(bn + nB) * Ktot + kq;

  const int iters = Ktot >> 5;
  uint4 av0 = ((const uint4*)ap)[0];
  uint4 av1 = ((const uint4*)ap)[1];
  uint4 bv = *(const uint4*)bp;
  for (int it = 0; it < iters; ++it) {
    *(uint4*)&As[rA * 40 + hk] = av0;
    *(uint4*)&As[rA * 40 + hk + 8] = av1;
    *(uint4*)&Bs[nB * 40 + kq] = bv;
    __syncthreads();
    if (it + 1 < iters) {  // prefetch next K-tile while MFMAs consume LDS
      const ushort* apn = ap + (it + 1) * 32;
      av0 = ((const uint4*)apn)[0];
      av1 = ((const uint4*)apn)[1];
      bv = *(const uint4*)(bp + (it + 1) * 32);
    }
    sfrag a0 = *(const sfrag*)&As[(w * 32 + ln) * 40 + quad * 8];
    sfrag a1 = *(const sfrag*)&As[(w * 32 + 16 + ln) * 40 + quad * 8];
#pragma unroll
    for (int nf = 0; nf < 4; ++nf) {
      sfrag b = *(const sfrag*)&Bs[(nf * 16 + ln) * 40 + quad * 8];
      acc[0][nf] = __builtin_amdgcn_mfma_f32_16x16x32_bf16(a0, b, acc[0][nf], 0, 0, 0);
      acc[1][nf] = __builtin_amdgcn_mfma_f32_16x16x32_bf16(a1, b, acc[1][nf], 0, 0, 0);
    }
    __syncthreads();
  }

  float bcol[4];
#pragma unroll
  for (int nf = 0; nf < 4; ++nf) bcol[nf] = bias[bn + nf * 16 + ln];
  float ssum[4] = {0.f, 0.f, 0.f, 0.f}, sqq[4] = {0.f, 0.f, 0.f, 0.f};
#pragma unroll
  for (int mf = 0; mf < 2; ++mf) {
    int rbase = bm + w * 32 + mf * 16 + quad * 4;
#pragma unroll
    for (int r = 0; r < 4; ++r) {
      int row = rbase + r;
      bool valid = row < NN;
      float d = valid ? degf[row] : 0.f;
#pragma unroll
      for (int nf = 0; nf < 4; ++nf) {
        float v = fmaxf(acc[mf][nf][r] + d * bcol[nf], 0.f);
        if (valid) {
          size_t oidx = (size_t)row * CHID + bn + nf * 16 + ln;
          outb[oidx] = f2b(v);
          int enc = __builtin_amdgcn_cvt_pk_fp8_f32(v, v, 0, false);
          out8[oidx] = (unsigned char)enc;
          ssum[nf] += v;
          sqq[nf] += v * v;
        }
      }
    }
  }
#pragma unroll
  for (int nf = 0; nf < 4; ++nf) {
    float s = ssum[nf], q = sqq[nf];
    s += __shfl_xor(s, 16); s += __shfl_xor(s, 32);
    q += __shfl_xor(q, 16); q += __shfl_xor(q, 32);
    if (quad == 0) {
      atomicAdd(&colsum[bn + nf * 16 + ln], s);
      atomicAdd(&colsq[bn + nf * 16 + ln], q);
    }
  }
}

// ---------------- fused: per-graph BN+relu pooling + MLP head (one block per graph) ----------------
__global__ __launch_bounds__(512) void k_poolmlp(const ushort* __restrict__ t3, const float* __restrict__ colsum,
                                                 const float* __restrict__ colsq, const float* __restrict__ g3,
                                                 const float* __restrict__ be3, const int* __restrict__ batch,
                                                 const float* __restrict__ nb, const float* __restrict__ w1,
                                                 const float* __restrict__ b1, const float* __restrict__ w2,
                                                 const float* __restrict__ b2, float* __restrict__ out) {
  int g = blockIdx.x;
  int t = threadIdx.x;
  __shared__ int sgs, sge;
  __shared__ f4 pq[8][64];                 // 8 row-offset partials x 64 col-groups
  __shared__ float zin[CHID + 1 + CIN];    // 385
  __shared__ float red[8];
  if (t == 0) { sgs = NN; sge = 0; }
  __syncthreads();
  for (int i = t; i < NN; i += 512) {
    if (batch[i] == g) { atomicMin(&sgs, i); atomicMax(&sge, i + 1); }
  }
  __syncthreads();
  int gs = sgs, ge = sge;
  int cnt = (ge > gs) ? (ge - gs) : 0;

  int cg = t & 63, off = t >> 6;
  int c0 = cg << 2;
  float scv[4], shv[4];
#pragma unroll
  for (int j = 0; j < 4; ++j) {
    int c = c0 + j;
    float mu = colsum[c] * (1.f / (float)NN);
    float var = colsq[c] * (1.f / (float)NN) - mu * mu;
    float inv = rsqrtf(var + 1e-5f);
    scv[j] = g3[c] * inv;
    shv[j] = be3[c] - mu * scv[j];
  }
  f4 acc = (f4){0.f, 0.f, 0.f, 0.f};
  for (int r = gs + off; r < ge; r += 8) {
    ushort4 tv = *(const ushort4*)&t3[(size_t)r * CHID + c0];
    acc.x += fmaxf(fmaf(b2f(tv.x), scv[0], shv[0]), 0.f);
    acc.y += fmaxf(fmaf(b2f(tv.y), scv[1], shv[1]), 0.f);
    acc.z += fmaxf(fmaf(b2f(tv.z), scv[2], shv[2]), 0.f);
    acc.w += fmaxf(fmaf(b2f(tv.w), scv[3], shv[3]), 0.f);
  }
  pq[off][cg] = acc;
  __syncthreads();
  if (t < CHID) {
    float s = 0.f;
#pragma unroll
    for (int o = 0; o < 8; ++o) s += ((const float*)&pq[o][t >> 2])[t & 3];
    zin[t] = s;
  } else if (t == CHID) zin[CHID] = (float)cnt * 0.025f;  // / MAX_SIZE(40)
  else if (t < CHID + 1 + CIN) zin[t] = nb[g * CIN + (t - CHID - 1)];
  __syncthreads();

  float acc1 = b1[t];
  for (int k = 0; k < CHID + 1 + CIN; ++k) acc1 = fmaf(zin[k], w1[k * CMLP + t], acc1);
  float z = fmaxf(acc1, 0.f);
  int wid = t >> 6, wl = t & 63;
#pragma unroll
  for (int n = 0; n < CNC; ++n) {
    float part = z * w2[t * CNC + n];
#pragma unroll
    for (int d = 1; d < 64; d <<= 1) part += __shfl_xor(part, d);
    if (wl == 0) red[wid] = part;
    __syncthreads();
    if (t == 0) {
      float tot = 0.f;
#pragma unroll
      for (int i = 0; i < 8; ++i) tot += red[i];
      out[g * CNC + n] = tot + b2[n];
    }
    __syncthreads();
  }
}

// ---------------- launch ----------------

extern "C" void kernel_launch(void* const* d_in, const int* in_sizes, int n_in,
                              void* d_out, int out_size, void* d_ws, size_t ws_size,
                              hipStream_t stream) {
  const float* x     = (const float*)d_in[0];
  const int*   ei    = (const int*)d_in[1];
  const float* eattr = (const float*)d_in[2];
  const int*   batch = (const int*)d_in[3];
  const float* nbr   = (const float*)d_in[4];
  const float* W1 = (const float*)d_in[5];
  const float* b1 = (const float*)d_in[6];
  const float* g1 = (const float*)d_in[7];
  const float* be1 = (const float*)d_in[8];
  const float* W2 = (const float*)d_in[9];
  const float* b2 = (const float*)d_in[10];
  const float* g2 = (const float*)d_in[11];
  const float* be2 = (const float*)d_in[12];
  const float* W3 = (const float*)d_in[13];
  const float* b3 = (const float*)d_in[14];
  const float* g3 = (const float*)d_in[15];
  const float* be3 = (const float*)d_in[16];
  const float* fc1w = (const float*)d_in[17];
  const float* fc1b = (const float*)d_in[18];
  const float* fc2w = (const float*)d_in[19];
  const float* fc2b = (const float*)d_in[20];
  float* out = (float*)d_out;

  char* ws = (char*)d_ws;
  size_t off = 0;
  auto alloc = [&](size_t bytes) {
    void* p = ws + off;
    off = (off + bytes + 255) & ~(size_t)255;
    return p;
  };
  int*    ptr    = (int*)alloc((NN + 1) * sizeof(int));   // histogram (zeroed by k_init)
  int*    rowp   = (int*)alloc((NN + 1) * sizeof(int));   // final CSR row starts
  int*    pos    = (int*)alloc(NN * sizeof(int));         // placement cursors
  float*  degf   = (float*)alloc(NN * sizeof(float));
  int*    srcs   = (int*)alloc(NE * sizeof(int));
  unsigned char* eattrs8 = (unsigned char*)alloc((size_t)(NE + 8) * CEC);  // 20.5 MB fp8 CSR-ordered
  ushort* A1     = (ushort*)alloc((size_t)NN * K1 * sizeof(ushort));
  ushort* A23    = (ushort*)alloc((size_t)NN * K23 * sizeof(ushort));
  ushort* Wt1    = (ushort*)alloc((size_t)256 * K1 * sizeof(ushort));
  ushort* Wt2    = (ushort*)alloc((size_t)256 * K23 * sizeof(ushort));
  ushort* Wt3    = (ushort*)alloc((size_t)256 * K23 * sizeof(ushort));
  ushort* xb     = (ushort*)alloc((size_t)NN * CIN * sizeof(ushort));
  ushort* tmp    = (ushort*)alloc((size_t)NN * CHID * sizeof(ushort));        // bf16 pre-BN h
  unsigned char* tmp8 = (unsigned char*)alloc((size_t)NN * CHID);             // fp8 pre-BN h (L2-resident)
  float*  stats  = (float*)alloc(6 * CHID * sizeof(float));  // [layer][sum|sq][256] (zeroed by k_init)
  (void)ws_size; (void)n_in; (void)in_sizes; (void)out_size;

  float* cs1 = stats + 0 * 512, *cq1 = stats + 0 * 512 + 256;
  float* cs2 = stats + 1 * 512, *cq2 = stats + 1 * 512 + 256;
  float* cs3 = stats + 2 * 512, *cq3 = stats + 2 * 512 + 256;

  // CSR build + prep (11 launches total)
  k_init<<<41 + 1250 + 1472, 256, 0, stream>>>(ptr, stats, (const float4*)x, xb,
                                               W1, W2, W3, Wt1, Wt2, Wt3);
  k_count<<<1250, 256, 0, stream>>>(ei, ptr);
  k_scan<<<1, 1024, 0, stream>>>(ptr, rowp, pos, degf);
  k_fillperm<<<20000, 256, 0, stream>>>(ei, pos, srcs, (const float4*)eattr, eattrs8);
  k_eag<<<NN / 4, 256, 0, stream>>>(eattrs8, x, degf, xb, rowp, srcs, A1, A23);

  dim3 ggrid(cdiv(NN, 128), CHID / 64);  // (79, 4)

  // layer 1
  k_gemm<<<ggrid, 256, 0, stream>>>(A1, Wt1, b1, degf, tmp, tmp8, cs1, cq1, K1);
  k_gbn<<<NN / 4, 256, 0, stream>>>(tmp, (const unsigned*)tmp8, cs1, cq1, g1, be1, rowp, srcs, degf, A23);

  // layer 2
  k_gemm<<<ggrid, 256, 0, stream>>>(A23, Wt2, b2, degf, tmp, tmp8, cs2, cq2, K23);
  k_gbn<<<NN / 4, 256, 0, stream>>>(tmp, (const unsigned*)tmp8, cs2, cq2, g2, be2, rowp, srcs, degf, A23);

  // layer 3
  k_gemm<<<ggrid, 256, 0, stream>>>(A23, Wt3, b3, degf, tmp, tmp8, cs3, cq3, K23);

  // fused pool + MLP head
  k_poolmlp<<<NB, 512, 0, stream>>>(tmp, cs3, cq3, g3, be3, batch, nbr,
                                    fc1w, fc1b, fc2w, fc2b, out);
}